// Round 6
// baseline (93.770 us; speedup 1.0000x reference)
//
#include <hip/hip_runtime.h>
#include <hip/hip_fp16.h>

#define NPTS 256
#define LEVELS 16
#define TABLE 4096
#define N_ENC 24
#define P_TOTAL (NPTS * NPTS)   // 65536
#define PRIME1 2654435761u
#define PRIME2 805459861u
#define ENTRY_H2 32   // half2 slots per 128B entry (24 used, 8 pad)

// ---------------------------------------------------------------------------
// tables[t][l][idx][f] (fp32) -> T2[l][idx][t] (half2, 128B-padded entries)
// ---------------------------------------------------------------------------
__global__ __launch_bounds__(256) void k_cvt(const float2* __restrict__ src,
                                             __half2* __restrict__ T2) {
    int tid = blockIdx.x * 256 + threadIdx.x;   // LEVELS*TABLE*N_ENC
    int t  = tid % N_ENC;
    int li = tid / N_ENC;          // l*TABLE + idx
    int l   = li >> 12;
    int idx = li & (TABLE - 1);
    float2 f = src[((t * LEVELS + l) * TABLE) + idx];
    T2[(size_t)li * ENTRY_H2 + t] =
        __halves2half2(__float2half_rn(f.x), __float2half_rn(f.y));
}

// ---------------------------------------------------------------------------
// Main kernel: one wave per point p. lane = l8*8 + q:
//   l8 = level octet: this lane owns levels {l8, l8+8}
//   q  = 16B chunk of the 128B entry (t = 4q..4q+3)
// Phase 1: compute all 16 (corner,level) offsets, issue all 16 dwordx4 loads
//          into a register array (16-deep memory pipeline).
// Phase 2: packed fp16 FMA accumulate. No cross-lane ops.
// ---------------------------------------------------------------------------
__global__ __launch_bounds__(256) void k_main(const float* __restrict__ xyz,
                                              const char* __restrict__ Tb,
                                              float* __restrict__ out) {
    const int lane = threadIdx.x & 63;
    const int p = blockIdx.x * 4 + (threadIdx.x >> 6);
    const int i = p >> 8, j = p & 255;
    const int l8 = lane >> 3;    // level octet
    const int q  = lane & 7;     // 16B chunk

    const float rx = xyz[i * 3 + 0] - xyz[j * 3 + 0];
    const float ry = xyz[i * 3 + 1] - xyz[j * 3 + 1];
    const float rz = xyz[i * 3 + 2] - xyz[j * 3 + 2];

    // Per-lane state for its two levels (h=0: level l8, h=1: level l8+8)
    unsigned hx0[2], hx1[2], hy0[2], hy1[2], hz0[2], hz1[2];
    float pw[2][4];              // xy-plane weight products
    float uz[2], wz[2];
    unsigned baseh[2];           // byte base: level<<19 (+ q*16)
#pragma unroll
    for (int h = 0; h < 2; ++h) {
        // RES = floor(20^(fl(1/15)*l)) in f64 = {1,1,1,1,2,2,3,4,4,6,7,8,10,13,16,19}
        const unsigned long long packed =
            h ? 0x13100D0A08070604ull : 0x0403020201010101ull;
        const float res = (float)((packed >> (l8 * 8)) & 0xFF);
        const float sx = rx * res, sy = ry * res, sz = rz * res;
        const float bx = floorf(sx), by = floorf(sy), bz = floorf(sz);
        const float wxx = sx - bx, wyy = sy - by;
        wz[h] = sz - bz; uz[h] = 1.0f - wz[h];
        const float uxx = 1.0f - wxx, uyy = 1.0f - wyy;
        pw[h][0] = uxx * uyy; pw[h][1] = wxx * uyy;
        pw[h][2] = uxx * wyy; pw[h][3] = wxx * wyy;
        hx0[h] = (unsigned)(int)bx;           hx1[h] = hx0[h] + 1u;
        hy0[h] = (unsigned)(int)by * PRIME1;  hy1[h] = hy0[h] + PRIME1;
        hz0[h] = (unsigned)(int)bz * PRIME2;  hz1[h] = hz0[h] + PRIME2;
        baseh[h] = ((unsigned)(l8 + 8 * h) << 19) + ((unsigned)q << 4);
    }

    // ---- Phase 1: issue all 16 gathers (k = c*2 + h) ----
    int4 raw[16];
#pragma unroll
    for (int k = 0; k < 16; ++k) {
        const int c = k >> 1, h = k & 1;
        const unsigned hsh = ((c & 1) ? hx1[h] : hx0[h])
                           ^ ((c & 2) ? hy1[h] : hy0[h])
                           ^ ((c & 4) ? hz1[h] : hz0[h]);
        const unsigned off = baseh[h] + ((hsh & (TABLE - 1u)) << 7);
        raw[k] = *(const int4*)(Tb + off);
    }

    // ---- Phase 2: weight + packed fp16 accumulate ----
    __half2 accA[4] = {}, accB[4] = {};
#pragma unroll
    for (int k = 0; k < 16; ++k) {
        const int c = k >> 1, h = k & 1;
        const float w = pw[h][c & 3] * ((c & 4) ? wz[h] : uz[h]);
        const __half2 wh = __float2half2_rn(w);
        __half2* acc = h ? accB : accA;      // h compile-time
        const int* cb = &raw[k].x;
#pragma unroll
        for (int r = 0; r < 4; ++r) {
            __half2 hv;
            __builtin_memcpy(&hv, &cb[r], 4);
            acc[r] = __hfma2(hv, wh, acc[r]);
        }
    }

    // lane (l8, q<6) holds t=4q+r for levels l8 (accA) and l8+8 (accB).
    // out[t][p][2l+f]: 8 l8-lanes store consecutive 8B -> 64B segments.
    if (q < 6) {
#pragma unroll
        for (int r = 0; r < 4; ++r) {
            const int t = 4 * q + r;
            float* base = out + (size_t)t * ((size_t)P_TOTAL * 32) + (size_t)p * 32;
            const float2 a = __half22float2(accA[r]);
            const float2 b = __half22float2(accB[r]);
            double da, db;
            __builtin_memcpy(&da, &a, 8);
            __builtin_memcpy(&db, &b, 8);
            __builtin_nontemporal_store(da, (double*)(base + 2 * l8));
            __builtin_nontemporal_store(db, (double*)(base + 2 * l8 + 16));
        }
    }
}

extern "C" void kernel_launch(void* const* d_in, const int* in_sizes, int n_in,
                              void* d_out, int out_size, void* d_ws, size_t ws_size,
                              hipStream_t stream) {
    const float* xyz    = (const float*)d_in[0];
    const float* tables = (const float*)d_in[1];
    float* out = (float*)d_out;

    // workspace: 16*4096*128B = 8 MB
    k_cvt<<<(LEVELS * TABLE * N_ENC) / 256, 256, 0, stream>>>(
        (const float2*)tables, (__half2*)d_ws);
    k_main<<<P_TOTAL / 4, 256, 0, stream>>>(xyz, (const char*)d_ws, out);
}

// Round 8
// 72.947 us; speedup vs baseline: 1.2854x; 1.2854x over previous
//
#include <hip/hip_runtime.h>
#include <hip/hip_fp16.h>

#define NPTS 256
#define TABLE 4096
#define N_ENC 24
#define P_TOTAL (NPTS * NPTS)   // 65536
#define PRIME1 2654435761u
#define PRIME2 805459861u
#define ENTRY_H2 32             // half2 slots per 128B entry (24 used, 8 pad)
#define N_CENT 28211            // total compacted entries (3.44 MB)

typedef float f32x4 __attribute__((ext_vector_type(4)));

// Compact layout: levels 0-10 dense by lattice index (D=2R+1 per axis),
// levels 11-15 full 4096 hashed buckets.
// bases B[l]; entries: {27,27,27,27,125,125,343,729,729,2197,3375,4096x5}

// ---------------------------------------------------------------------------
// Rebuild: compacted fp16 table. For lattice levels, evaluate the hash per
// cell (collisions duplicate values -> results identical to reference).
// ---------------------------------------------------------------------------
__global__ __launch_bounds__(256) void k_build(const float2* __restrict__ src,
                                               __half2* __restrict__ T2) {
    const int tid = blockIdx.x * 256 + threadIdx.x;
    if (tid >= N_CENT * N_ENC) return;
    const int t = tid % N_ENC;
    const int e = tid / N_ENC;
    constexpr int B[17] = {0,27,54,81,108,233,358,701,1430,2159,4356,
                           7731,11827,15923,20019,24115,28211};
    constexpr int Rv[16] = {1,1,1,1,2,2,3,4,4,6,7,8,10,13,16,19};
#pragma unroll
    for (int l = 0; l < 16; ++l) {
        if (e >= B[l] && e < B[l + 1]) {
            const int local = e - B[l];
            int hash;
            if (l <= 10) {
                const int R = Rv[l], D = 2 * R + 1;
                const int x = local / (D * D), rem = local - x * (D * D);
                const int y = rem / D, z = rem - y * D;
                hash = (int)((((unsigned)(x - R))
                            ^ ((unsigned)(y - R)) * PRIME1
                            ^ ((unsigned)(z - R)) * PRIME2) & (TABLE - 1u));
            } else {
                hash = local;
            }
            const float2 f = src[((t * 16 + l) * TABLE) + hash];
            T2[(size_t)e * ENTRY_H2 + t] =
                __halves2half2(__float2half_rn(f.x), __float2half_rn(f.y));
        }
    }
}

// ---------------------------------------------------------------------------
// Main kernel: one wave per point p. lane = l8*8 + q:
//   l8: this lane owns the level PAIR {2*l8, 2*l8+1}  (adjacent -> 16B stores)
//   q : 16B chunk of the 128B entry (t = 4q..4q+3)
// Phase 1: all 16 (corner,h) offsets -> 16 dwordx4 loads in flight.
//   levels <=10: dense lattice addressing; levels >=11: hash addressing.
// Phase 2: packed fp16 FMA accumulate (identical arithmetic to prior rounds).
// ---------------------------------------------------------------------------
__global__ __launch_bounds__(256) void k_main(const float* __restrict__ xyz,
                                              const char* __restrict__ Tb,
                                              float* __restrict__ out) {
    const int lane = threadIdx.x & 63;
    const int p = blockIdx.x * 4 + (threadIdx.x >> 6);
    const int i = p >> 8, j = p & 255;
    const int l8 = lane >> 3;    // level pair index
    const int q  = lane & 7;     // 16B chunk

    const float rx = xyz[i * 3 + 0] - xyz[j * 3 + 0];
    const float ry = xyz[i * 3 + 1] - xyz[j * 3 + 1];
    const float rz = xyz[i * 3 + 2] - xyz[j * 3 + 2];

    // Packed per-level constants (byte/short fields, level order):
    // RES = floor(20^(fl(1/15)*l)) = {1,1,1,1,2,2,3,4,4,6,7,8,10,13,16,19}
    const unsigned long long RESLO = 0x0403020201010101ull;
    const unsigned long long RESHI = 0x13100D0A08070604ull;
    const unsigned long long DLO   = 0x0907050503030303ull;  // D=2R+1 (compact lvls)
    const unsigned long long DHI   = 0x00000000000F0D09ull;
    const unsigned long long C0    = 0x00510036001B0000ull;  // bases l0-3
    const unsigned long long C1    = 0x02BD016600E9006Cull;  // l4-7
    const unsigned long long C2    = 0x1E331104086F0596ull;  // l8-11
    const unsigned long long C3    = 0x5E334E333E332E33ull;  // l12-15

    // Per-lane state for its two levels (h: level = 2*l8 + h)
    unsigned hx0[2], hx1[2], hy0[2], hy1[2], hz0[2], hz1[2], hbase[2];
    unsigned addrC[2], DDs[2], Dbs[2];
    bool cmp[2];
    float pw[2][4], uzv[2], wzv[2];
#pragma unroll
    for (int h = 0; h < 2; ++h) {
        const int level = 2 * l8 + h;
        const unsigned shift8 = (level & 7) * 8;
        const float res = (float)((((l8 < 4) ? RESLO : RESHI) >> shift8) & 0xFF);
        const int   R   = (int)res;
        const int   D   = (int)((((l8 < 4) ? DLO : DHI) >> shift8) & 0xFF);
        const unsigned long long Bw = (l8 < 2) ? C0 : (l8 < 4) ? C1
                                    : (l8 < 6) ? C2 : C3;
        const unsigned base = (unsigned)((Bw >> ((level & 3) * 16)) & 0xFFFF);
        cmp[h] = (l8 <= 5 - h);                 // level <= 10

        const float sx = rx * res, sy = ry * res, sz = rz * res;
        const float bx = floorf(sx), by = floorf(sy), bz = floorf(sz);
        const float wxx = sx - bx, wyy = sy - by;
        wzv[h] = sz - bz; uzv[h] = 1.0f - wzv[h];
        const float uxx = 1.0f - wxx, uyy = 1.0f - wyy;
        pw[h][0] = uxx * uyy; pw[h][1] = wxx * uyy;
        pw[h][2] = uxx * wyy; pw[h][3] = wxx * wyy;

        const int bxi = (int)bx, byi = (int)by, bzi = (int)bz;
        // hashed path
        hx0[h] = (unsigned)bxi;          hx1[h] = hx0[h] + 1u;
        hy0[h] = (unsigned)byi * PRIME1; hy1[h] = hy0[h] + PRIME1;
        hz0[h] = (unsigned)bzi * PRIME2; hz1[h] = hz0[h] + PRIME2;
        hbase[h] = (base << 7) + ((unsigned)q << 4);
        // compact (lattice) path
        const int iA = ((bxi + R) * D + (byi + R)) * D + (bzi + R);
        addrC[h] = ((base + (unsigned)iA) << 7) + ((unsigned)q << 4);
        DDs[h] = (unsigned)(D * D) << 7;
        Dbs[h] = (unsigned)D << 7;
    }

    // ---- Phase 1: issue all 16 gathers (k = c*2 + h) ----
    int4 raw[16];
#pragma unroll
    for (int k = 0; k < 16; ++k) {
        const int c = k >> 1, h = k & 1;
        unsigned offC = addrC[h];
        if (c & 1) offC += DDs[h];
        if (c & 2) offC += Dbs[h];
        if (c & 4) offC += 128u;
        const unsigned hsh = ((c & 1) ? hx1[h] : hx0[h])
                           ^ ((c & 2) ? hy1[h] : hy0[h])
                           ^ ((c & 4) ? hz1[h] : hz0[h]);
        const unsigned offH = hbase[h] + ((hsh & (TABLE - 1u)) << 7);
        const unsigned off = cmp[h] ? offC : offH;
        raw[k] = *(const int4*)(Tb + off);
    }

    // ---- Phase 2: weight + packed fp16 accumulate ----
    __half2 accA[4] = {}, accB[4] = {};
#pragma unroll
    for (int k = 0; k < 16; ++k) {
        const int c = k >> 1, h = k & 1;
        const float w = pw[h][c & 3] * ((c & 4) ? wzv[h] : uzv[h]);
        const __half2 wh = __float2half2_rn(w);
        __half2* acc = h ? accB : accA;      // h compile-time
        const int* cb = &raw[k].x;
#pragma unroll
        for (int r = 0; r < 4; ++r) {
            __half2 hv;
            __builtin_memcpy(&hv, &cb[r], 4);
            acc[r] = __hfma2(hv, wh, acc[r]);
        }
    }

    // lane (l8, q<6) holds t=4q+r, levels {2l8, 2l8+1} -> one 16B store.
    // Wave covers out[t][p][0..31] as full 128B lines.
    if (q < 6) {
#pragma unroll
        for (int r = 0; r < 4; ++r) {
            const int t = 4 * q + r;
            const float2 a = __half22float2(accA[r]);   // level 2l8
            const float2 b = __half22float2(accB[r]);   // level 2l8+1
            f32x4 v;
            v.x = a.x; v.y = a.y; v.z = b.x; v.w = b.y;
            float* dst = out + (size_t)t * ((size_t)P_TOTAL * 32)
                             + (size_t)p * 32 + 4 * l8;
            __builtin_nontemporal_store(v, (f32x4*)dst);
        }
    }
}

extern "C" void kernel_launch(void* const* d_in, const int* in_sizes, int n_in,
                              void* d_out, int out_size, void* d_ws, size_t ws_size,
                              hipStream_t stream) {
    const float* xyz    = (const float*)d_in[0];
    const float* tables = (const float*)d_in[1];
    float* out = (float*)d_out;

    // workspace: 28211 * 128B = 3.44 MB (< per-XCD L2)
    const int nb = (N_CENT * N_ENC + 255) / 256;
    k_build<<<nb, 256, 0, stream>>>((const float2*)tables, (__half2*)d_ws);
    k_main<<<P_TOTAL / 4, 256, 0, stream>>>(xyz, (const char*)d_ws, out);
}